// Round 7
// baseline (313.428 us; speedup 1.0000x reference)
//
#include <hip/hip_runtime.h>
#include <stdint.h>

// ROI max pooling, image-centric rewrite.
//   img:  (1, 200, 200, 512) fp32, NHWC
//   rois: (1, 128, 4) fp32 as (x, y, w, h)
//   pool: 7  ->  out: (1, 128, 7, 7, 512) fp32
//
// R7 theory: R1-R6 all saturate ~6.7 TB/s of DEMAND traffic (340 MB =
// sum of roi areas x 2KB); per-(roi,bin) blocks can't reduce it (bins are
// disjoint). Invert: tile the IMAGE, read each byte exactly once (82 MB)
// into LDS via global_load_lds DMA, compute clipped bin-maxes from LDS,
// merge across tiles with atomicMax on order-preserving flip-encoded
// uint32 (exact for all finite floats; max is order-independent).
// 4 dispatches: init(enc(-inf)) -> bounds -> scatter -> decode.
//
// Bin boundaries use the same strict fp32 ops as before (bit-exact vs ref).

#define IMG_H 200
#define IMG_W 200
#define IMG_C 512
#define POOL 7
#define NROI 128

#define YT 8           // tile rows
#define XT 16          // tile cols
#define NYT (IMG_H / YT)            // 25
#define NXT ((IMG_W + XT - 1) / XT) // 13
#define NQ  (IMG_C / 64)            // 8 ch-slices of 64 ch (256 B/px)

#define OUT_N (NROI * POOL * POOL * IMG_C)   // 3,211,264 dwords

#define AS1(p) ((const __attribute__((address_space(1))) void*)(p))
#define AS3(p) ((__attribute__((address_space(3))) void*)(p))

__device__ __forceinline__ float4 max4(float4 a, float4 b) {
    return make_float4(fmaxf(a.x, b.x), fmaxf(a.y, b.y),
                       fmaxf(a.z, b.z), fmaxf(a.w, b.w));
}

// Order-preserving float->uint encoding (monotone for all finite floats).
__device__ __forceinline__ unsigned enc(float f) {
    unsigned u = __float_as_uint(f);
    return ((int)u < 0) ? ~u : (u | 0x80000000u);
}

// ---------- kernel 1: init output to enc(-inf) = 0x007FFFFF ----------
__global__ __launch_bounds__(256) void init_kernel(uint4* __restrict__ out) {
    const unsigned i = blockIdx.x * 256 + threadIdx.x;   // grid covers exactly OUT_N/4
    out[i] = make_uint4(0x007FFFFFu, 0x007FFFFFu, 0x007FFFFFu, 0x007FFFFFu);
}

// ---------- kernel 2: per-roi bin boundaries (strict fp32, bit-exact) ----------
__global__ __launch_bounds__(128) void bounds_kernel(
    const float* __restrict__ rois, int* __restrict__ bnd) {
    const int r = threadIdx.x;   // 0..127
    const float rx = rois[r * 4 + 0];
    const float ry = rois[r * 4 + 1];
    const float rw = rois[r * 4 + 2];
    const float rh = rois[r * 4 + 3];
    const float sx = __fdiv_rn(rw, 7.0f);
    const float sy = __fdiv_rn(rh, 7.0f);
    #pragma unroll
    for (int k = 0; k <= 7; ++k) {
        bnd[r * 16 + k]     = (int)__fadd_rn(rx, __fmul_rn((float)k, sx));
        bnd[r * 16 + 8 + k] = (int)__fadd_rn(ry, __fmul_rn((float)k, sy));
    }
}

// ---------- kernel 3: image-centric scatter-max ----------
__global__ __launch_bounds__(64) void scatter_kernel(
    const float* __restrict__ img,
    const int* __restrict__ bnd,
    unsigned* __restrict__ out)
{
    __shared__ float lds[YT * XT * 64];   // [row][px][64ch] = 32 KB

    const int b  = blockIdx.x;
    const int q  = b & 7;                 // ch-slice (64 ch)
    const int t  = b >> 3;
    const int ty0 = (t / NXT) * YT;
    const int tx0 = (t % NXT) * XT;
    const int ty1 = ty0 + YT;             // always <= 200
    const int tx1 = min(tx0 + XT, IMG_W);

    const int lane = threadIdx.x;
    const int slot = lane & 15;           // float4 within 64-ch slice
    const int pgrp = lane >> 4;           // 0..3: pixel subgroup

    // ---- stage tile slice into LDS, fire-and-forget DMA (vmcnt) ----
    // lane l of inst (r,k) fetches px = tx0+4k+pgrp (clamped), bytes
    // [slot*16, slot*16+16) of the 256 B ch-slice; LDS dest = uniform
    // base + lane*16 -> layout [r][4k+pgrp][slot].
    const char* gb = (const char*)img + q * 256 + slot * 16;
    #pragma unroll
    for (int r = 0; r < YT; ++r) {
        const size_t rowoff = (size_t)(ty0 + r) * IMG_W;
        #pragma unroll
        for (int k = 0; k < 4; ++k) {
            const int pxg = min(tx0 + 4 * k + pgrp, IMG_W - 1);
            const char* gp = gb + (rowoff + pxg) * (size_t)2048;
            __builtin_amdgcn_global_load_lds(AS1(gp),
                AS3(&lds[(r * XT + 4 * k) * 64]), 16, 0, 0);
        }
    }

    // ---- roi filter (scalar loads, lgkmcnt — overlaps the DMA) ----
    unsigned long long m0 = 0ull, m1 = 0ull;
    for (int roi = 0; roi < NROI; ++roi) {
        const int bx0 = bnd[roi * 16 + 0];
        const int bx7 = bnd[roi * 16 + 7];
        const int by0 = bnd[roi * 16 + 8];
        const int by7 = bnd[roi * 16 + 15];
        const bool hit = (bx0 < tx1) & (bx7 > tx0) & (by0 < ty1) & (by7 > ty0);
        if (roi < 64) m0 |= (unsigned long long)hit << roi;
        else          m1 |= (unsigned long long)hit << (roi - 64);
    }

    __builtin_amdgcn_s_waitcnt(0x0F70);   // vmcnt(0): tile staged
    if (!(m0 | m1)) return;

    for (int roi = 0; roi < NROI; ++roi) {
        const bool hit = (roi < 64) ? ((m0 >> roi) & 1ull)
                                    : ((m1 >> (roi - 64)) & 1ull);
        if (!hit) continue;

        int bx[8], by[8];
        #pragma unroll
        for (int k = 0; k <= 7; ++k) {
            bx[k] = bnd[roi * 16 + k];
            by[k] = bnd[roi * 16 + 8 + k];
        }

        for (int jy = 0; jy < POOL; ++jy) {
            const int yA = max(by[jy],     ty0);
            const int yB = min(by[jy + 1], ty1);
            if (yA >= yB) continue;
            for (int ix = 0; ix < POOL; ++ix) {
                const int xA = max(bx[ix],     tx0);
                const int xB = min(bx[ix + 1], tx1);
                if (xA >= xB) continue;

                float4 m = make_float4(-INFINITY, -INFINITY, -INFINITY, -INFINITY);
                const int nIt = (xB - xA + 3) >> 2;
                for (int yy = yA; yy < yB; ++yy) {
                    const int rb = (yy - ty0) * XT - tx0;
                    for (int it = 0; it < nIt; ++it) {
                        const int px = min(xA + 4 * it + pgrp, xB - 1); // clamp: dup, idempotent
                        const float4* p = (const float4*)&lds[(rb + px) * 64 + slot * 4];
                        m = max4(m, *p);
                    }
                }
                // reduce across the 4 pixel subgroups (lanes ^16, ^32)
                m.x = fmaxf(m.x, __shfl_xor(m.x, 16, 64));
                m.y = fmaxf(m.y, __shfl_xor(m.y, 16, 64));
                m.z = fmaxf(m.z, __shfl_xor(m.z, 16, 64));
                m.w = fmaxf(m.w, __shfl_xor(m.w, 16, 64));
                m.x = fmaxf(m.x, __shfl_xor(m.x, 32, 64));
                m.y = fmaxf(m.y, __shfl_xor(m.y, 32, 64));
                m.z = fmaxf(m.z, __shfl_xor(m.z, 32, 64));
                m.w = fmaxf(m.w, __shfl_xor(m.w, 32, 64));

                if (pgrp == 0) {
                    unsigned* o = out +
                        (((unsigned)roi * 49 + jy * 7 + ix) * IMG_C + q * 64 + slot * 4);
                    atomicMax(o + 0, enc(m.x));
                    atomicMax(o + 1, enc(m.y));
                    atomicMax(o + 2, enc(m.z));
                    atomicMax(o + 3, enc(m.w));
                }
            }
        }
    }
}

// ---------- kernel 4: decode in place ----------
__global__ __launch_bounds__(256) void decode_kernel(unsigned* __restrict__ out) {
    const unsigned i = (blockIdx.x * 256 + threadIdx.x) * 4;
    uint4 u = *(const uint4*)(out + i);
    float4 f;
    f.x = (u.x & 0x80000000u) ? __uint_as_float(u.x ^ 0x80000000u) : __uint_as_float(~u.x);
    f.y = (u.y & 0x80000000u) ? __uint_as_float(u.y ^ 0x80000000u) : __uint_as_float(~u.y);
    f.z = (u.z & 0x80000000u) ? __uint_as_float(u.z ^ 0x80000000u) : __uint_as_float(~u.z);
    f.w = (u.w & 0x80000000u) ? __uint_as_float(u.w ^ 0x80000000u) : __uint_as_float(~u.w);
    *(float4*)(out + i) = f;
}

extern "C" void kernel_launch(void* const* d_in, const int* in_sizes, int n_in,
                              void* d_out, int out_size, void* d_ws, size_t ws_size,
                              hipStream_t stream) {
    (void)in_sizes; (void)n_in; (void)ws_size; (void)out_size;
    const float* img  = (const float*)d_in[0];
    const float* rois = (const float*)d_in[1];
    unsigned* out = (unsigned*)d_out;
    int* bnd = (int*)d_ws;   // 128 rois x 16 ints = 8 KB

    // OUT_N = 3,211,264 dwords = 802,816 uint4 = 3136 blocks x 256 threads
    init_kernel<<<dim3(OUT_N / 4 / 256), dim3(256), 0, stream>>>((uint4*)out);
    bounds_kernel<<<dim3(1), dim3(128), 0, stream>>>(rois, bnd);
    scatter_kernel<<<dim3(NYT * NXT * NQ), dim3(64), 0, stream>>>(img, bnd, out);
    decode_kernel<<<dim3(OUT_N / 4 / 256), dim3(256), 0, stream>>>(out);
}